// Round 6
// baseline (346.152 us; speedup 1.0000x reference)
//
#include <hip/hip_runtime.h>
#include <hip/hip_bf16.h>

typedef unsigned short ushort_t;
typedef unsigned int uint_t;
typedef __attribute__((ext_vector_type(8))) short bf16x8;
typedef __attribute__((ext_vector_type(4))) float f32x4;

#define MFMA32(a, b, c) __builtin_amdgcn_mfma_f32_16x16x32_bf16(a, b, c, 0, 0, 0)

static constexpr int BATCH = 16;
static constexpr int SEQ   = 4096;   // H*W
static constexpr int CH    = 128;
static constexpr int NGRP  = 32;
static constexpr float EPS = 1e-6f;
// softmax scale folded into exp2 domain AND pre-folded into Q projection:
static constexpr float C2 = 0.08838834764831845f * 1.4426950408889634f;

__device__ inline ushort_t f2bf(float f) {
    uint_t u = __float_as_uint(f);
    u = (u + 0x7fff + ((u >> 16) & 1)) >> 16;
    return (ushort_t)u;
}

// bare v_exp_f32 via the PROPER intrinsic (no inline asm: r16 showed asm
// versions defeat register promotion -> scratch spills, WRITE_SIZE 16->36MB).
// Args bounded |x|<~35 in this kernel -> in-range, matches exp2f there.
__device__ inline float exp2_fast(float x) {
    return __builtin_amdgcn_exp2f(x);
}

// ---------------- GroupNorm partial sums (fp32 input) ----------------
// grid 256 = batch(16) x chunk(16); block 256. Writes RAW (sum, sumsq).
__global__ void gn_partial(const float* __restrict__ x, float* __restrict__ stats) {
    int bid = blockIdx.x;
    int b = bid >> 4, chunk = bid & 15;
    int t = threadIdx.x;
    int c4 = (t & 31) * 4;   // one group = 4 channels
    int rowoff = t >> 5;     // 0..7
    const float* xb = x + (size_t)b * SEQ * CH;
    float s1 = 0.f, s2 = 0.f;
    int base_row = chunk * 256;
    for (int i = 0; i < 32; ++i) {
        int r = base_row + i * 8 + rowoff;
        float4 v = *(const float4*)(xb + (size_t)r * CH + c4);
        s1 += v.x + v.y + v.z + v.w;
        s2 += v.x * v.x + v.y * v.y + v.z * v.z + v.w * v.w;
    }
    __shared__ float red[256][2];
    red[t][0] = s1; red[t][1] = s2;
    __syncthreads();
    if (t < 32) {
        float a1 = 0.f, a2 = 0.f;
        for (int ro = 0; ro < 8; ++ro) {
            a1 += red[ro * 32 + t][0];
            a2 += red[ro * 32 + t][1];
        }
        atomicAdd(&stats[(b * NGRP + t) * 2 + 0], a1);
        atomicAdd(&stats[(b * NGRP + t) * 2 + 1], a2);
    }
}

// ---------------- fused normalize + QKV GEMM (finalize inlined) ----------------
// q output pre-scaled by C2; v written TRANSPOSED: vt[b][d][seq]
__global__ __launch_bounds__(256) void gemm_qkv(const float* __restrict__ x,
                                                const float* __restrict__ stats,
                                                const float* __restrict__ gsc,
                                                const float* __restrict__ gbi,
                                                const float* __restrict__ Wq,
                                                const float* __restrict__ Wk,
                                                const float* __restrict__ Wv,
                                                const float* __restrict__ Bq,
                                                const float* __restrict__ Bk,
                                                const float* __restrict__ Bv,
                                                ushort_t* __restrict__ outq,
                                                ushort_t* __restrict__ outk,
                                                ushort_t* __restrict__ outvt) {
    __shared__ ushort_t lds_a[128][136];  // full 128x128 normalized A tile (bf16)
    __shared__ ushort_t lds_w[128][72];   // W^T half-tile [n][k_local]
    __shared__ float2 gstat[32];
    int t = threadIdx.x;
    int wv = t >> 6, lane = t & 63, quad = lane >> 4, l16 = lane & 15;
    size_t m0 = (size_t)blockIdx.x * 128;
    int batch = (int)(m0 >> 12);
    int seq0  = (int)(m0 & 4095);
    // inline gn_finalize for this batch
    if (t < 32) {
        float sum = stats[(batch * NGRP + t) * 2 + 0];
        float sq  = stats[(batch * NGRP + t) * 2 + 1];
        float mean = sum / 16384.f;
        float var  = sq / 16384.f - mean * mean;
        gstat[t] = float2{mean, __frsqrt_rn(var + EPS)};
    }
    __syncthreads();
    // stage A once, normalizing x -> h in flight
    for (int i = 0; i < 8; ++i) {
        int idx = (t + i * 256) * 8;
        int r = idx >> 7, c = idx & 127;
        size_t row = m0 + r;
        float4 xa = *(const float4*)(x + row * CH + c);
        float4 xc = *(const float4*)(x + row * CH + c + 4);
        float2 stA = gstat[c >> 2];
        float2 stB = gstat[(c >> 2) + 1];
        float4 sA = *(const float4*)(gsc + c), sB = *(const float4*)(gsc + c + 4);
        float4 bA = *(const float4*)(gbi + c), bB = *(const float4*)(gbi + c + 4);
        ushort_t tmp[8];
        tmp[0] = f2bf((xa.x - stA.x) * stA.y * sA.x + bA.x);
        tmp[1] = f2bf((xa.y - stA.x) * stA.y * sA.y + bA.y);
        tmp[2] = f2bf((xa.z - stA.x) * stA.y * sA.z + bA.z);
        tmp[3] = f2bf((xa.w - stA.x) * stA.y * sA.w + bA.w);
        tmp[4] = f2bf((xc.x - stB.x) * stB.y * sB.x + bB.x);
        tmp[5] = f2bf((xc.y - stB.x) * stB.y * sB.y + bB.y);
        tmp[6] = f2bf((xc.z - stB.x) * stB.y * sB.z + bB.z);
        tmp[7] = f2bf((xc.w - stB.x) * stB.y * sB.w + bB.w);
        *(uint4*)&lds_a[r][c] = *(const uint4*)tmp;
    }
    for (int j = 0; j < 3; ++j) {
        const float* W  = (j == 0) ? Wq : (j == 1) ? Wk : Wv;
        const float* Bi = (j == 0) ? Bq : (j == 1) ? Bk : Bv;
        f32x4 acc[2][8] = {};
        for (int kh = 0; kh < 2; ++kh) {
            int k0 = kh * 64;
            __syncthreads();   // protect lds_w reuse (also orders A staging before first read)
            for (int i = 0; i < 8; ++i) {
                int idx = (t + i * 256) * 4;     // flat = kl*128 + n
                int kl = idx >> 7, n = idx & 127;
                float4 wf = *(const float4*)(W + (size_t)(k0 + kl) * CH + n);
                lds_w[n + 0][kl] = f2bf(wf.x);
                lds_w[n + 1][kl] = f2bf(wf.y);
                lds_w[n + 2][kl] = f2bf(wf.z);
                lds_w[n + 3][kl] = f2bf(wf.w);
            }
            __syncthreads();
            for (int ks = 0; ks < 2; ++ks) {
                bf16x8 afrag[2];
                for (int tr = 0; tr < 2; ++tr)
                    afrag[tr] = *(const bf16x8*)&lds_a[wv * 32 + tr * 16 + l16][k0 + ks * 32 + quad * 8];
                for (int tc = 0; tc < 8; ++tc) {
                    bf16x8 bfrag = *(const bf16x8*)&lds_w[tc * 16 + l16][ks * 32 + quad * 8];
                    for (int tr = 0; tr < 2; ++tr)
                        acc[tr][tc] = MFMA32(afrag[tr], bfrag, acc[tr][tc]);
                }
            }
        }
        // epilogue
        for (int tc = 0; tc < 8; ++tc) {
            int col = tc * 16 + l16;
            float bval = Bi[col];
            for (int tr = 0; tr < 2; ++tr) {
                int rl = wv * 32 + tr * 16 + quad * 4;
                for (int r = 0; r < 4; ++r) {
                    float vv = acc[tr][tc][r] + bval;
                    if (j == 0) vv *= C2;   // fold softmax scale into q
                    if (j == 2) {
                        outvt[(size_t)batch * CH * SEQ + (size_t)col * SEQ + seq0 + rl + r] = f2bf(vv);
                    } else {
                        ushort_t* op = (j == 0) ? outq : outk;
                        op[(m0 + rl + r) * CH + col] = f2bf(vv);
                    }
                }
            }
        }
    }
}

// ---------------- flash attention r17: r15 pipeline + compiler-visible diet --
// r16 post-mortem: inline-asm exp2/cvt_pk DID cut VALUBusy 50.6->23.5 but
// regressed the wall 168.8->193us: asm outputs defeated register promotion
// (pb[] -> scratch; WRITE_SIZE 16->36MB) and cvt_pk changed rounding (absmax
// 0.031->0.084).  r17 = r15 EXACTLY, plus only the compiler-visible subset:
// (1) __builtin_amdgcn_exp2f — real intrinsic, bare v_exp_f32, schedulable,
// promotable, same in-range semantics; (2) s_setprio(1/0) around the fused
// MFMA block (T5, proven +4-7% on attn with wave role diversity).  Packs stay
// __float22bfloat162_rn (RNE, absmax-preserving).  Structure: cross-iteration
// pipeline (QK_{i+1} fused with PV_i), unnormalized exp2 softmax, dbuf,
// 1 barrier/iter.
__global__ __launch_bounds__(256, 2) void flash_attn17(const ushort_t* __restrict__ q,
                                                       const ushort_t* __restrict__ k,
                                                       const ushort_t* __restrict__ vt,
                                                       ushort_t* __restrict__ o) {
    int bid = blockIdx.x;
    int b = bid & 15, qt = bid >> 4;
    int t = threadIdx.x;
    int wv = t >> 6, lane = t & 63, quad = lane >> 4, l16 = lane & 15;
    const size_t SB = (size_t)SEQ * CH;
    const ushort_t* qb  = q  + (size_t)b * SB;
    const ushort_t* kb  = k  + (size_t)b * SB;
    const ushort_t* vtb = vt + (size_t)b * SB;   // [d][seq]

    __shared__ ushort_t lds_k[2][64][136];    // [buf][key][d]
    __shared__ ushort_t lds_vt[2][128][72];   // [buf][d][key_local PERMUTED]

    int qrow_base = qt * 128 + wv * 32;       // 4 waves x 32 q-rows
    // Q^T B-fragments for both 16-row halves (n=qrow=l16, k=d=quad*8+j)
    bf16x8 qfrag[2][4];
#pragma unroll
    for (int nt = 0; nt < 2; ++nt)
#pragma unroll
        for (int ks = 0; ks < 4; ++ks)
            qfrag[nt][ks] = *(const bf16x8*)(qb + (size_t)(qrow_base + nt * 16 + l16) * CH + ks * 32 + quad * 8);

    f32x4 oacc[8][2] = {};        // [mt=d/16][nt]
    float psum[2] = {0.f, 0.f};   // per-lane partial row-sums (reduced at end)

    // staging geometry (256 threads stage the full 64-key K and V^T tiles:
    // 4 rounds of 16B each)
    int kr_row  = t >> 4;          // 0..15 (+16i)
    int kr_col  = (t & 15) * 8;
    int vr_d    = t >> 3;          // 0..31 (+32i)
    int vr_beta = t & 7;
    int vc0 = 32 * (vr_beta >> 2) + 16 * (vr_beta & 1) + 4 * ((vr_beta >> 1) & 1);

    const ushort_t* kp = kb + (size_t)kr_row * CH + kr_col;
    const ushort_t* vp = vtb + (size_t)vr_d * SEQ + vr_beta * 8;

    uint4 kr[4], vr[4], k1[4];
    // prologue: load K0, V0, K1; write K0->lds_k[0], V0->lds_vt[0], K1->lds_k[1]
#pragma unroll
    for (int i = 0; i < 4; ++i) kr[i] = *(const uint4*)(kp + (size_t)i * 16 * CH);
#pragma unroll
    for (int i = 0; i < 4; ++i) vr[i] = *(const uint4*)(vp + (size_t)i * 32 * SEQ);
#pragma unroll
    for (int i = 0; i < 4; ++i) k1[i] = *(const uint4*)(kp + (size_t)(64 + i * 16) * CH);
    kp += 2 * 64 * CH;   // -> tile 2
    vp += 64;            // -> tile 1
#pragma unroll
    for (int i = 0; i < 4; ++i) {
        *(uint4*)&lds_k[0][kr_row + 16 * i][kr_col] = kr[i];
        *(uint4*)&lds_k[1][kr_row + 16 * i][kr_col] = k1[i];
        *(uint2*)&lds_vt[0][vr_d + 32 * i][vc0]     = uint2{vr[i].x, vr[i].y};
        *(uint2*)&lds_vt[0][vr_d + 32 * i][vc0 + 8] = uint2{vr[i].z, vr[i].w};
    }
    __syncthreads();

    // prologue compute: QK_0 -> pkp_0 (unnormalized exp2)
    bf16x8 pkp[2][2];   // [nt][half], live across iterations
    {
        f32x4 s[4][2] = {};
#pragma unroll
        for (int ks = 0; ks < 4; ++ks) {
            bf16x8 kf[4];
#pragma unroll
            for (int kt = 0; kt < 4; ++kt)
                kf[kt] = *(const bf16x8*)&lds_k[0][kt * 16 + l16][ks * 32 + quad * 8];
#pragma unroll
            for (int kt = 0; kt < 4; ++kt) {
                s[kt][0] = MFMA32(kf[kt], qfrag[0][ks], s[kt][0]);
                s[kt][1] = MFMA32(kf[kt], qfrag[1][ks], s[kt][1]);
            }
        }
#pragma unroll
        for (int nt = 0; nt < 2; ++nt) {
            float ps = 0.f;
            uint_t pb[8];
#pragma unroll
            for (int kt = 0; kt < 4; ++kt) {
                float p0 = exp2_fast(s[kt][nt][0]);
                float p1 = exp2_fast(s[kt][nt][1]);
                float p2 = exp2_fast(s[kt][nt][2]);
                float p3 = exp2_fast(s[kt][nt][3]);
                ps += (p0 + p1) + (p2 + p3);
                __hip_bfloat162 h01 = __float22bfloat162_rn(float2{p0, p1});
                __hip_bfloat162 h23 = __float22bfloat162_rn(float2{p2, p3});
                __builtin_memcpy(&pb[kt * 2 + 0], &h01, 4);
                __builtin_memcpy(&pb[kt * 2 + 1], &h23, 4);
            }
            psum[nt] += ps;
            __builtin_memcpy(&pkp[nt][0], &pb[0], 16);
            __builtin_memcpy(&pkp[nt][1], &pb[4], 16);
        }
    }
    __syncthreads();   // all waves done reading lds_k[0] before iter0 overwrites it

    // main loop: iter it computes PV(tile it) + QK(tile it+1)
    for (int it = 0; it < 63; ++it) {
        int knxt = (it + 1) & 1;   // K_{it+1} read buffer; also V_{it+1} write buffer
        int vcur = it & 1;         // V_it read buffer;    also K_{it+2} write buffer
        // issue loads: K_{it+2}, V_{it+1} (it=62 reads K one tile past the end:
        // lands in the adjacent vt workspace buffer, values never used)
#pragma unroll
        for (int i = 0; i < 4; ++i) kr[i] = *(const uint4*)(kp + (size_t)i * 16 * CH);
#pragma unroll
        for (int i = 0; i < 4; ++i) vr[i] = *(const uint4*)(vp + (size_t)i * 32 * SEQ);
        kp += 64 * CH; vp += 64;

        // fused MFMA block: QK_{it+1} (lds_k[knxt]) interleaved with
        // PV_it (lds_vt[vcur], pkp from previous iteration) — independent
        // dep-streams, back-to-back MFMA issue.  setprio biases the CU
        // scheduler toward this wave while the sibling is in softmax/staging.
        __builtin_amdgcn_s_setprio(1);
        f32x4 s[4][2] = {};
#pragma unroll
        for (int u = 0; u < 4; ++u) {
            bf16x8 kf[4];
#pragma unroll
            for (int kt = 0; kt < 4; ++kt)
                kf[kt] = *(const bf16x8*)&lds_k[knxt][kt * 16 + l16][u * 32 + quad * 8];
#pragma unroll
            for (int kt = 0; kt < 4; ++kt) {
                s[kt][0] = MFMA32(kf[kt], qfrag[0][u], s[kt][0]);
                s[kt][1] = MFMA32(kf[kt], qfrag[1][u], s[kt][1]);
            }
#pragma unroll
            for (int m2 = 0; m2 < 2; ++m2) {
                int mt = u * 2 + m2;
                bf16x8 vf0 = *(const bf16x8*)&lds_vt[vcur][mt * 16 + l16][quad * 8];
                bf16x8 vf1 = *(const bf16x8*)&lds_vt[vcur][mt * 16 + l16][32 + quad * 8];
                oacc[mt][0] = MFMA32(vf0, pkp[0][0], oacc[mt][0]);
                oacc[mt][0] = MFMA32(vf1, pkp[0][1], oacc[mt][0]);
                oacc[mt][1] = MFMA32(vf0, pkp[1][0], oacc[mt][1]);
                oacc[mt][1] = MFMA32(vf1, pkp[1][1], oacc[mt][1]);
            }
        }
        __builtin_amdgcn_s_setprio(0);

        // softmax(tile it+1) -> pkp for next iteration (overlaps store tail)
#pragma unroll
        for (int nt = 0; nt < 2; ++nt) {
            float ps = 0.f;
            uint_t pb[8];
#pragma unroll
            for (int kt = 0; kt < 4; ++kt) {
                float p0 = exp2_fast(s[kt][nt][0]);
                float p1 = exp2_fast(s[kt][nt][1]);
                float p2 = exp2_fast(s[kt][nt][2]);
                float p3 = exp2_fast(s[kt][nt][3]);
                ps += (p0 + p1) + (p2 + p3);
                __hip_bfloat162 h01 = __float22bfloat162_rn(float2{p0, p1});
                __hip_bfloat162 h23 = __float22bfloat162_rn(float2{p2, p3});
                __builtin_memcpy(&pb[kt * 2 + 0], &h01, 4);
                __builtin_memcpy(&pb[kt * 2 + 1], &h23, 4);
            }
            psum[nt] += ps;
            __builtin_memcpy(&pkp[nt][0], &pb[0], 16);
            __builtin_memcpy(&pkp[nt][1], &pb[4], 16);
        }

        // stage writes: K_{it+2} -> lds_k[vcur], V_{it+1} -> lds_vt[knxt]
        // (both regions last READ in iter it-1; ordered by that barrier)
#pragma unroll
        for (int i = 0; i < 4; ++i) {
            *(uint4*)&lds_k[vcur][kr_row + 16 * i][kr_col] = kr[i];
            *(uint2*)&lds_vt[knxt][vr_d + 32 * i][vc0]     = uint2{vr[i].x, vr[i].y};
            *(uint2*)&lds_vt[knxt][vr_d + 32 * i][vc0 + 8] = uint2{vr[i].z, vr[i].w};
        }
        __syncthreads();   // single barrier per iteration
    }

    // epilogue: PV for tile 63 (lds_vt[1], pkp_63 computed at it=62)
#pragma unroll
    for (int mt = 0; mt < 8; ++mt) {
        bf16x8 vf0 = *(const bf16x8*)&lds_vt[1][mt * 16 + l16][quad * 8];
        bf16x8 vf1 = *(const bf16x8*)&lds_vt[1][mt * 16 + l16][32 + quad * 8];
        oacc[mt][0] = MFMA32(vf0, pkp[0][0], oacc[mt][0]);
        oacc[mt][0] = MFMA32(vf1, pkp[0][1], oacc[mt][0]);
        oacc[mt][1] = MFMA32(vf0, pkp[1][0], oacc[mt][1]);
        oacc[mt][1] = MFMA32(vf1, pkp[1][1], oacc[mt][1]);
    }

    // epilogue: cross-lane row-sum reduce (ONCE), then O[qrow][d] = O^T / l
#pragma unroll
    for (int nt = 0; nt < 2; ++nt) {
        float tot = psum[nt];
        tot += __shfl_xor(tot, 16, 64);
        tot += __shfl_xor(tot, 32, 64);
        float inv = 1.f / tot;
        size_t row = (size_t)b * SEQ + qrow_base + nt * 16 + l16;
#pragma unroll
        for (int mt = 0; mt < 8; ++mt) {
            ushort_t tmp[4];
#pragma unroll
            for (int r = 0; r < 4; ++r) tmp[r] = f2bf(oacc[mt][nt][r] * inv);
            *(uint2*)&o[row * CH + mt * 16 + quad * 4] = *(const uint2*)tmp;
        }
    }
}

// ---------------- final GEMM: out = A_bf16 @ W + bias + resid (fp32 out) ----------------
__global__ __launch_bounds__(256) void gemm_out(const ushort_t* __restrict__ A,
                                                const float* __restrict__ W,
                                                const float* __restrict__ bias,
                                                const float* __restrict__ resid,
                                                float* __restrict__ out) {
    __shared__ ushort_t lds_a[128][72];
    __shared__ ushort_t lds_w[128][72];
    int t = threadIdx.x;
    int wv = t >> 6, lane = t & 63, quad = lane >> 4, l16 = lane & 15;
    size_t m0 = (size_t)blockIdx.x * 128;
    f32x4 acc[2][8] = {};
    for (int kh = 0; kh < 2; ++kh) {
        int k0 = kh * 64;
        __syncthreads();
        for (int i = 0; i < 4; ++i) {
            int idx = (t + i * 256) * 8;
            int r = idx >> 6, c = idx & 63;
            *(uint4*)&lds_a[r][c] = *(const uint4*)(A + (m0 + r) * CH + k0 + c);
        }
        for (int i = 0; i < 8; ++i) {
            int idx = (t + i * 256) * 4;
            int kl = idx >> 7, n = idx & 127;
            float4 wf = *(const float4*)(W + (size_t)(k0 + kl) * CH + n);
            lds_w[n + 0][kl] = f2bf(wf.x);
            lds_w[n + 1][kl] = f2bf(wf.y);
            lds_w[n + 2][kl] = f2bf(wf.z);
            lds_w[n + 3][kl] = f2bf(wf.w);
        }
        __syncthreads();
        for (int ks = 0; ks < 2; ++ks) {
            bf16x8 afrag[2];
            for (int tr = 0; tr < 2; ++tr)
                afrag[tr] = *(const bf16x8*)&lds_a[wv * 32 + tr * 16 + l16][ks * 32 + quad * 8];
            for (int tc = 0; tc < 8; ++tc) {
                bf16x8 bfrag = *(const bf16x8*)&lds_w[tc * 16 + l16][ks * 32 + quad * 8];
                for (int tr = 0; tr < 2; ++tr)
                    acc[tr][tc] = MFMA32(afrag[tr], bfrag, acc[tr][tc]);
            }
        }
    }
    for (int tc = 0; tc < 8; ++tc) {
        int col = tc * 16 + l16;
        float bval = bias[col];
        for (int tr = 0; tr < 2; ++tr) {
            int rl = wv * 32 + tr * 16 + quad * 4;
            for (int r = 0; r < 4; ++r) {
                size_t row = m0 + rl + r;
                out[row * CH + col] = acc[tr][tc][r] + bval + resid[row * CH + col];
            }
        }
    }
}

extern "C" void kernel_launch(void* const* d_in, const int* in_sizes, int n_in,
                              void* d_out, int out_size, void* d_ws, size_t ws_size,
                              hipStream_t stream) {
    const float* x   = (const float*)d_in[0];
    const float* gsc = (const float*)d_in[1];
    const float* gbi = (const float*)d_in[2];
    const float* wq  = (const float*)d_in[3];
    const float* bq  = (const float*)d_in[4];
    const float* wk  = (const float*)d_in[5];
    const float* bk  = (const float*)d_in[6];
    const float* wvp = (const float*)d_in[7];
    const float* bv  = (const float*)d_in[8];
    const float* wo  = (const float*)d_in[9];
    const float* bo  = (const float*)d_in[10];
    float* outp = (float*)d_out;

    const size_t NELEM = (size_t)BATCH * SEQ * CH;  // 8388608
    float*    stats = (float*)d_ws;
    ushort_t* qbuf  = (ushort_t*)((char*)d_ws + 4096);
    ushort_t* kbuf  = qbuf + NELEM;
    ushort_t* vtbuf = kbuf + NELEM;
    ushort_t* abuf  = vtbuf + NELEM;   // attention output
    // note: flash_attn17 prefetches one K tile past the K buffer end (reads
    // land in vtbuf; values unused) — keep buffer order qbuf,kbuf,vtbuf,abuf.

    hipMemsetAsync(stats, 0, BATCH * NGRP * 2 * sizeof(float), stream);
    gn_partial<<<256, 256, 0, stream>>>(x, stats);
    gemm_qkv<<<512, 256, 0, stream>>>(x, stats, gsc, gbi, wq, wk, wvp, bq, bk, bv,
                                      qbuf, kbuf, vtbuf);
    flash_attn17<<<512, 256, 0, stream>>>(qbuf, kbuf, vtbuf, abuf);
    gemm_out<<<512, 256, 0, stream>>>(abuf, wo, bo, x, outp);
}

// Round 7
// 299.865 us; speedup vs baseline: 1.1544x; 1.1544x over previous
//
#include <hip/hip_runtime.h>
#include <hip/hip_bf16.h>

typedef unsigned short ushort_t;
typedef unsigned int uint_t;
typedef __attribute__((ext_vector_type(8))) short bf16x8;
typedef __attribute__((ext_vector_type(4))) float f32x4;

#define MFMA32(a, b, c) __builtin_amdgcn_mfma_f32_16x16x32_bf16(a, b, c, 0, 0, 0)

static constexpr int BATCH = 16;
static constexpr int SEQ   = 4096;   // H*W
static constexpr int CH    = 128;
static constexpr int NGRP  = 32;
static constexpr float EPS = 1e-6f;
// softmax scale folded into exp2 domain AND pre-folded into Q projection:
static constexpr float C2 = 0.08838834764831845f * 1.4426950408889634f;

__device__ inline ushort_t f2bf(float f) {
    uint_t u = __float_as_uint(f);
    u = (u + 0x7fff + ((u >> 16) & 1)) >> 16;
    return (ushort_t)u;
}

// bare v_exp_f32 via the clang intrinsic (schedulable, promotable — no inline
// asm).  Args bounded |x|<~35 in this kernel -> in-range, matches exp2f.
__device__ inline float exp2_fast(float x) {
    return __builtin_amdgcn_exp2f(x);
}

// ---------------- GroupNorm partial sums (fp32 input) ----------------
// grid 256 = batch(16) x chunk(16); block 256. Writes RAW (sum, sumsq).
__global__ void gn_partial(const float* __restrict__ x, float* __restrict__ stats) {
    int bid = blockIdx.x;
    int b = bid >> 4, chunk = bid & 15;
    int t = threadIdx.x;
    int c4 = (t & 31) * 4;   // one group = 4 channels
    int rowoff = t >> 5;     // 0..7
    const float* xb = x + (size_t)b * SEQ * CH;
    float s1 = 0.f, s2 = 0.f;
    int base_row = chunk * 256;
    for (int i = 0; i < 32; ++i) {
        int r = base_row + i * 8 + rowoff;
        float4 v = *(const float4*)(xb + (size_t)r * CH + c4);
        s1 += v.x + v.y + v.z + v.w;
        s2 += v.x * v.x + v.y * v.y + v.z * v.z + v.w * v.w;
    }
    __shared__ float red[256][2];
    red[t][0] = s1; red[t][1] = s2;
    __syncthreads();
    if (t < 32) {
        float a1 = 0.f, a2 = 0.f;
        for (int ro = 0; ro < 8; ++ro) {
            a1 += red[ro * 32 + t][0];
            a2 += red[ro * 32 + t][1];
        }
        atomicAdd(&stats[(b * NGRP + t) * 2 + 0], a1);
        atomicAdd(&stats[(b * NGRP + t) * 2 + 1], a2);
    }
}

// ---------------- fused normalize + QKV GEMM (finalize inlined) ----------------
// q output pre-scaled by C2; v written TRANSPOSED: vt[b][d][seq]
__global__ __launch_bounds__(256) void gemm_qkv(const float* __restrict__ x,
                                                const float* __restrict__ stats,
                                                const float* __restrict__ gsc,
                                                const float* __restrict__ gbi,
                                                const float* __restrict__ Wq,
                                                const float* __restrict__ Wk,
                                                const float* __restrict__ Wv,
                                                const float* __restrict__ Bq,
                                                const float* __restrict__ Bk,
                                                const float* __restrict__ Bv,
                                                ushort_t* __restrict__ outq,
                                                ushort_t* __restrict__ outk,
                                                ushort_t* __restrict__ outvt) {
    __shared__ ushort_t lds_a[128][136];  // full 128x128 normalized A tile (bf16)
    __shared__ ushort_t lds_w[128][72];   // W^T half-tile [n][k_local]
    __shared__ float2 gstat[32];
    int t = threadIdx.x;
    int wv = t >> 6, lane = t & 63, quad = lane >> 4, l16 = lane & 15;
    size_t m0 = (size_t)blockIdx.x * 128;
    int batch = (int)(m0 >> 12);
    int seq0  = (int)(m0 & 4095);
    // inline gn_finalize for this batch
    if (t < 32) {
        float sum = stats[(batch * NGRP + t) * 2 + 0];
        float sq  = stats[(batch * NGRP + t) * 2 + 1];
        float mean = sum / 16384.f;
        float var  = sq / 16384.f - mean * mean;
        gstat[t] = float2{mean, __frsqrt_rn(var + EPS)};
    }
    __syncthreads();
    // stage A once, normalizing x -> h in flight
    for (int i = 0; i < 8; ++i) {
        int idx = (t + i * 256) * 8;
        int r = idx >> 7, c = idx & 127;
        size_t row = m0 + r;
        float4 xa = *(const float4*)(x + row * CH + c);
        float4 xc = *(const float4*)(x + row * CH + c + 4);
        float2 stA = gstat[c >> 2];
        float2 stB = gstat[(c >> 2) + 1];
        float4 sA = *(const float4*)(gsc + c), sB = *(const float4*)(gsc + c + 4);
        float4 bA = *(const float4*)(gbi + c), bB = *(const float4*)(gbi + c + 4);
        ushort_t tmp[8];
        tmp[0] = f2bf((xa.x - stA.x) * stA.y * sA.x + bA.x);
        tmp[1] = f2bf((xa.y - stA.x) * stA.y * sA.y + bA.y);
        tmp[2] = f2bf((xa.z - stA.x) * stA.y * sA.z + bA.z);
        tmp[3] = f2bf((xa.w - stA.x) * stA.y * sA.w + bA.w);
        tmp[4] = f2bf((xc.x - stB.x) * stB.y * sB.x + bB.x);
        tmp[5] = f2bf((xc.y - stB.x) * stB.y * sB.y + bB.y);
        tmp[6] = f2bf((xc.z - stB.x) * stB.y * sB.z + bB.z);
        tmp[7] = f2bf((xc.w - stB.x) * stB.y * sB.w + bB.w);
        *(uint4*)&lds_a[r][c] = *(const uint4*)tmp;
    }
    for (int j = 0; j < 3; ++j) {
        const float* W  = (j == 0) ? Wq : (j == 1) ? Wk : Wv;
        const float* Bi = (j == 0) ? Bq : (j == 1) ? Bk : Bv;
        f32x4 acc[2][8] = {};
        for (int kh = 0; kh < 2; ++kh) {
            int k0 = kh * 64;
            __syncthreads();   // protect lds_w reuse (also orders A staging before first read)
            for (int i = 0; i < 8; ++i) {
                int idx = (t + i * 256) * 4;     // flat = kl*128 + n
                int kl = idx >> 7, n = idx & 127;
                float4 wf = *(const float4*)(W + (size_t)(k0 + kl) * CH + n);
                lds_w[n + 0][kl] = f2bf(wf.x);
                lds_w[n + 1][kl] = f2bf(wf.y);
                lds_w[n + 2][kl] = f2bf(wf.z);
                lds_w[n + 3][kl] = f2bf(wf.w);
            }
            __syncthreads();
            for (int ks = 0; ks < 2; ++ks) {
                bf16x8 afrag[2];
                for (int tr = 0; tr < 2; ++tr)
                    afrag[tr] = *(const bf16x8*)&lds_a[wv * 32 + tr * 16 + l16][k0 + ks * 32 + quad * 8];
                for (int tc = 0; tc < 8; ++tc) {
                    bf16x8 bfrag = *(const bf16x8*)&lds_w[tc * 16 + l16][ks * 32 + quad * 8];
                    for (int tr = 0; tr < 2; ++tr)
                        acc[tr][tc] = MFMA32(afrag[tr], bfrag, acc[tr][tc]);
                }
            }
        }
        // epilogue
        for (int tc = 0; tc < 8; ++tc) {
            int col = tc * 16 + l16;
            float bval = Bi[col];
            for (int tr = 0; tr < 2; ++tr) {
                int rl = wv * 32 + tr * 16 + quad * 4;
                for (int r = 0; r < 4; ++r) {
                    float vv = acc[tr][tc][r] + bval;
                    if (j == 0) vv *= C2;   // fold softmax scale into q
                    if (j == 2) {
                        outvt[(size_t)batch * CH * SEQ + (size_t)col * SEQ + seq0 + rl + r] = f2bf(vv);
                    } else {
                        ushort_t* op = (j == 0) ? outq : outk;
                        op[(m0 + rl + r) * CH + col] = f2bf(vv);
                    }
                }
            }
        }
    }
}

// ---------------- flash attention r18: r15 + cheap exp2 ONLY (A/B isolate) ---
// r16/r17 post-mortem: both bundled {cheap exp2 + s_setprio} and both landed
// at 193us with ~17MB/dispatch of anomalous HBM traffic (WRITE 16.4->30MB)
// despite VALUBusy halving — at only 116 VGPR, i.e. scheduling-induced
// scratch/eviction churn, not pressure spill.  Prime suspect: s_setprio's
// side-effecting region pinning the scheduler around the MFMA block (FETCH
// signatures identical across r16/r17 despite different softmax codegen).
// r18 isolates the other variable: EXACT r15 structure (loads -> fused MFMA
// -> softmax -> staging -> barrier, no setprio), only exp2f ->
// __builtin_amdgcn_exp2f.  If WRITE_SIZE returns to 16384KB and the wall
// drops below 168, fast-exp2 is safe and setprio was the poison.
__global__ __launch_bounds__(256, 2) void flash_attn18(const ushort_t* __restrict__ q,
                                                       const ushort_t* __restrict__ k,
                                                       const ushort_t* __restrict__ vt,
                                                       ushort_t* __restrict__ o) {
    int bid = blockIdx.x;
    int b = bid & 15, qt = bid >> 4;
    int t = threadIdx.x;
    int wv = t >> 6, lane = t & 63, quad = lane >> 4, l16 = lane & 15;
    const size_t SB = (size_t)SEQ * CH;
    const ushort_t* qb  = q  + (size_t)b * SB;
    const ushort_t* kb  = k  + (size_t)b * SB;
    const ushort_t* vtb = vt + (size_t)b * SB;   // [d][seq]

    __shared__ ushort_t lds_k[2][64][136];    // [buf][key][d]
    __shared__ ushort_t lds_vt[2][128][72];   // [buf][d][key_local PERMUTED]

    int qrow_base = qt * 128 + wv * 32;       // 4 waves x 32 q-rows
    // Q^T B-fragments for both 16-row halves (n=qrow=l16, k=d=quad*8+j)
    bf16x8 qfrag[2][4];
#pragma unroll
    for (int nt = 0; nt < 2; ++nt)
#pragma unroll
        for (int ks = 0; ks < 4; ++ks)
            qfrag[nt][ks] = *(const bf16x8*)(qb + (size_t)(qrow_base + nt * 16 + l16) * CH + ks * 32 + quad * 8);

    f32x4 oacc[8][2] = {};        // [mt=d/16][nt]
    float psum[2] = {0.f, 0.f};   // per-lane partial row-sums (reduced at end)

    // staging geometry (256 threads stage the full 64-key K and V^T tiles:
    // 4 rounds of 16B each)
    int kr_row  = t >> 4;          // 0..15 (+16i)
    int kr_col  = (t & 15) * 8;
    int vr_d    = t >> 3;          // 0..31 (+32i)
    int vr_beta = t & 7;
    int vc0 = 32 * (vr_beta >> 2) + 16 * (vr_beta & 1) + 4 * ((vr_beta >> 1) & 1);

    const ushort_t* kp = kb + (size_t)kr_row * CH + kr_col;
    const ushort_t* vp = vtb + (size_t)vr_d * SEQ + vr_beta * 8;

    uint4 kr[4], vr[4], k1[4];
    // prologue: load K0, V0, K1; write K0->lds_k[0], V0->lds_vt[0], K1->lds_k[1]
#pragma unroll
    for (int i = 0; i < 4; ++i) kr[i] = *(const uint4*)(kp + (size_t)i * 16 * CH);
#pragma unroll
    for (int i = 0; i < 4; ++i) vr[i] = *(const uint4*)(vp + (size_t)i * 32 * SEQ);
#pragma unroll
    for (int i = 0; i < 4; ++i) k1[i] = *(const uint4*)(kp + (size_t)(64 + i * 16) * CH);
    kp += 2 * 64 * CH;   // -> tile 2
    vp += 64;            // -> tile 1
#pragma unroll
    for (int i = 0; i < 4; ++i) {
        *(uint4*)&lds_k[0][kr_row + 16 * i][kr_col] = kr[i];
        *(uint4*)&lds_k[1][kr_row + 16 * i][kr_col] = k1[i];
        *(uint2*)&lds_vt[0][vr_d + 32 * i][vc0]     = uint2{vr[i].x, vr[i].y};
        *(uint2*)&lds_vt[0][vr_d + 32 * i][vc0 + 8] = uint2{vr[i].z, vr[i].w};
    }
    __syncthreads();

    // prologue compute: QK_0 -> pkp_0 (unnormalized exp2)
    bf16x8 pkp[2][2];   // [nt][half], live across iterations
    {
        f32x4 s[4][2] = {};
#pragma unroll
        for (int ks = 0; ks < 4; ++ks) {
            bf16x8 kf[4];
#pragma unroll
            for (int kt = 0; kt < 4; ++kt)
                kf[kt] = *(const bf16x8*)&lds_k[0][kt * 16 + l16][ks * 32 + quad * 8];
#pragma unroll
            for (int kt = 0; kt < 4; ++kt) {
                s[kt][0] = MFMA32(kf[kt], qfrag[0][ks], s[kt][0]);
                s[kt][1] = MFMA32(kf[kt], qfrag[1][ks], s[kt][1]);
            }
        }
#pragma unroll
        for (int nt = 0; nt < 2; ++nt) {
            float ps = 0.f;
            uint_t pb[8];
#pragma unroll
            for (int kt = 0; kt < 4; ++kt) {
                float p0 = exp2_fast(s[kt][nt][0]);
                float p1 = exp2_fast(s[kt][nt][1]);
                float p2 = exp2_fast(s[kt][nt][2]);
                float p3 = exp2_fast(s[kt][nt][3]);
                ps += (p0 + p1) + (p2 + p3);
                __hip_bfloat162 h01 = __float22bfloat162_rn(float2{p0, p1});
                __hip_bfloat162 h23 = __float22bfloat162_rn(float2{p2, p3});
                __builtin_memcpy(&pb[kt * 2 + 0], &h01, 4);
                __builtin_memcpy(&pb[kt * 2 + 1], &h23, 4);
            }
            psum[nt] += ps;
            __builtin_memcpy(&pkp[nt][0], &pb[0], 16);
            __builtin_memcpy(&pkp[nt][1], &pb[4], 16);
        }
    }
    __syncthreads();   // all waves done reading lds_k[0] before iter0 overwrites it

    // main loop: iter it computes PV(tile it) + QK(tile it+1)
    for (int it = 0; it < 63; ++it) {
        int knxt = (it + 1) & 1;   // K_{it+1} read buffer; also V_{it+1} write buffer
        int vcur = it & 1;         // V_it read buffer;    also K_{it+2} write buffer
        // issue loads: K_{it+2}, V_{it+1} (it=62 reads K one tile past the end:
        // lands in the adjacent vt workspace buffer, values never used)
#pragma unroll
        for (int i = 0; i < 4; ++i) kr[i] = *(const uint4*)(kp + (size_t)i * 16 * CH);
#pragma unroll
        for (int i = 0; i < 4; ++i) vr[i] = *(const uint4*)(vp + (size_t)i * 32 * SEQ);
        kp += 64 * CH; vp += 64;

        // fused MFMA block: QK_{it+1} (lds_k[knxt]) interleaved with
        // PV_it (lds_vt[vcur], pkp from previous iteration) — independent
        // dep-streams, back-to-back MFMA issue.
        f32x4 s[4][2] = {};
#pragma unroll
        for (int u = 0; u < 4; ++u) {
            bf16x8 kf[4];
#pragma unroll
            for (int kt = 0; kt < 4; ++kt)
                kf[kt] = *(const bf16x8*)&lds_k[knxt][kt * 16 + l16][u * 32 + quad * 8];
#pragma unroll
            for (int kt = 0; kt < 4; ++kt) {
                s[kt][0] = MFMA32(kf[kt], qfrag[0][u], s[kt][0]);
                s[kt][1] = MFMA32(kf[kt], qfrag[1][u], s[kt][1]);
            }
#pragma unroll
            for (int m2 = 0; m2 < 2; ++m2) {
                int mt = u * 2 + m2;
                bf16x8 vf0 = *(const bf16x8*)&lds_vt[vcur][mt * 16 + l16][quad * 8];
                bf16x8 vf1 = *(const bf16x8*)&lds_vt[vcur][mt * 16 + l16][32 + quad * 8];
                oacc[mt][0] = MFMA32(vf0, pkp[0][0], oacc[mt][0]);
                oacc[mt][0] = MFMA32(vf1, pkp[0][1], oacc[mt][0]);
                oacc[mt][1] = MFMA32(vf0, pkp[1][0], oacc[mt][1]);
                oacc[mt][1] = MFMA32(vf1, pkp[1][1], oacc[mt][1]);
            }
        }

        // softmax(tile it+1) -> pkp for next iteration (overlaps store tail)
#pragma unroll
        for (int nt = 0; nt < 2; ++nt) {
            float ps = 0.f;
            uint_t pb[8];
#pragma unroll
            for (int kt = 0; kt < 4; ++kt) {
                float p0 = exp2_fast(s[kt][nt][0]);
                float p1 = exp2_fast(s[kt][nt][1]);
                float p2 = exp2_fast(s[kt][nt][2]);
                float p3 = exp2_fast(s[kt][nt][3]);
                ps += (p0 + p1) + (p2 + p3);
                __hip_bfloat162 h01 = __float22bfloat162_rn(float2{p0, p1});
                __hip_bfloat162 h23 = __float22bfloat162_rn(float2{p2, p3});
                __builtin_memcpy(&pb[kt * 2 + 0], &h01, 4);
                __builtin_memcpy(&pb[kt * 2 + 1], &h23, 4);
            }
            psum[nt] += ps;
            __builtin_memcpy(&pkp[nt][0], &pb[0], 16);
            __builtin_memcpy(&pkp[nt][1], &pb[4], 16);
        }

        // stage writes: K_{it+2} -> lds_k[vcur], V_{it+1} -> lds_vt[knxt]
        // (both regions last READ in iter it-1; ordered by that barrier)
#pragma unroll
        for (int i = 0; i < 4; ++i) {
            *(uint4*)&lds_k[vcur][kr_row + 16 * i][kr_col] = kr[i];
            *(uint2*)&lds_vt[knxt][vr_d + 32 * i][vc0]     = uint2{vr[i].x, vr[i].y};
            *(uint2*)&lds_vt[knxt][vr_d + 32 * i][vc0 + 8] = uint2{vr[i].z, vr[i].w};
        }
        __syncthreads();   // single barrier per iteration
    }

    // epilogue: PV for tile 63 (lds_vt[1], pkp_63 computed at it=62)
#pragma unroll
    for (int mt = 0; mt < 8; ++mt) {
        bf16x8 vf0 = *(const bf16x8*)&lds_vt[1][mt * 16 + l16][quad * 8];
        bf16x8 vf1 = *(const bf16x8*)&lds_vt[1][mt * 16 + l16][32 + quad * 8];
        oacc[mt][0] = MFMA32(vf0, pkp[0][0], oacc[mt][0]);
        oacc[mt][0] = MFMA32(vf1, pkp[0][1], oacc[mt][0]);
        oacc[mt][1] = MFMA32(vf0, pkp[1][0], oacc[mt][1]);
        oacc[mt][1] = MFMA32(vf1, pkp[1][1], oacc[mt][1]);
    }

    // epilogue: cross-lane row-sum reduce (ONCE), then O[qrow][d] = O^T / l
#pragma unroll
    for (int nt = 0; nt < 2; ++nt) {
        float tot = psum[nt];
        tot += __shfl_xor(tot, 16, 64);
        tot += __shfl_xor(tot, 32, 64);
        float inv = 1.f / tot;
        size_t row = (size_t)b * SEQ + qrow_base + nt * 16 + l16;
#pragma unroll
        for (int mt = 0; mt < 8; ++mt) {
            ushort_t tmp[4];
#pragma unroll
            for (int r = 0; r < 4; ++r) tmp[r] = f2bf(oacc[mt][nt][r] * inv);
            *(uint2*)&o[row * CH + mt * 16 + quad * 4] = *(const uint2*)tmp;
        }
    }
}

// ---------------- final GEMM: out = A_bf16 @ W + bias + resid (fp32 out) ----------------
__global__ __launch_bounds__(256) void gemm_out(const ushort_t* __restrict__ A,
                                                const float* __restrict__ W,
                                                const float* __restrict__ bias,
                                                const float* __restrict__ resid,
                                                float* __restrict__ out) {
    __shared__ ushort_t lds_a[128][72];
    __shared__ ushort_t lds_w[128][72];
    int t = threadIdx.x;
    int wv = t >> 6, lane = t & 63, quad = lane >> 4, l16 = lane & 15;
    size_t m0 = (size_t)blockIdx.x * 128;
    f32x4 acc[2][8] = {};
    for (int kh = 0; kh < 2; ++kh) {
        int k0 = kh * 64;
        __syncthreads();
        for (int i = 0; i < 4; ++i) {
            int idx = (t + i * 256) * 8;
            int r = idx >> 6, c = idx & 63;
            *(uint4*)&lds_a[r][c] = *(const uint4*)(A + (m0 + r) * CH + k0 + c);
        }
        for (int i = 0; i < 8; ++i) {
            int idx = (t + i * 256) * 4;
            int kl = idx >> 7, n = idx & 127;
            float4 wf = *(const float4*)(W + (size_t)(k0 + kl) * CH + n);
            lds_w[n + 0][kl] = f2bf(wf.x);
            lds_w[n + 1][kl] = f2bf(wf.y);
            lds_w[n + 2][kl] = f2bf(wf.z);
            lds_w[n + 3][kl] = f2bf(wf.w);
        }
        __syncthreads();
        for (int ks = 0; ks < 2; ++ks) {
            bf16x8 afrag[2];
            for (int tr = 0; tr < 2; ++tr)
                afrag[tr] = *(const bf16x8*)&lds_a[wv * 32 + tr * 16 + l16][ks * 32 + quad * 8];
            for (int tc = 0; tc < 8; ++tc) {
                bf16x8 bfrag = *(const bf16x8*)&lds_w[tc * 16 + l16][ks * 32 + quad * 8];
                for (int tr = 0; tr < 2; ++tr)
                    acc[tr][tc] = MFMA32(afrag[tr], bfrag, acc[tr][tc]);
            }
        }
    }
    for (int tc = 0; tc < 8; ++tc) {
        int col = tc * 16 + l16;
        float bval = bias[col];
        for (int tr = 0; tr < 2; ++tr) {
            int rl = wv * 32 + tr * 16 + quad * 4;
            for (int r = 0; r < 4; ++r) {
                size_t row = m0 + rl + r;
                out[row * CH + col] = acc[tr][tc][r] + bval + resid[row * CH + col];
            }
        }
    }
}

extern "C" void kernel_launch(void* const* d_in, const int* in_sizes, int n_in,
                              void* d_out, int out_size, void* d_ws, size_t ws_size,
                              hipStream_t stream) {
    const float* x   = (const float*)d_in[0];
    const float* gsc = (const float*)d_in[1];
    const float* gbi = (const float*)d_in[2];
    const float* wq  = (const float*)d_in[3];
    const float* bq  = (const float*)d_in[4];
    const float* wk  = (const float*)d_in[5];
    const float* bk  = (const float*)d_in[6];
    const float* wvp = (const float*)d_in[7];
    const float* bv  = (const float*)d_in[8];
    const float* wo  = (const float*)d_in[9];
    const float* bo  = (const float*)d_in[10];
    float* outp = (float*)d_out;

    const size_t NELEM = (size_t)BATCH * SEQ * CH;  // 8388608
    float*    stats = (float*)d_ws;
    ushort_t* qbuf  = (ushort_t*)((char*)d_ws + 4096);
    ushort_t* kbuf  = qbuf + NELEM;
    ushort_t* vtbuf = kbuf + NELEM;
    ushort_t* abuf  = vtbuf + NELEM;   // attention output
    // note: flash_attn18 prefetches one K tile past the K buffer end (reads
    // land in vtbuf; values unused) — keep buffer order qbuf,kbuf,vtbuf,abuf.

    hipMemsetAsync(stats, 0, BATCH * NGRP * 2 * sizeof(float), stream);
    gn_partial<<<256, 256, 0, stream>>>(x, stats);
    gemm_qkv<<<512, 256, 0, stream>>>(x, stats, gsc, gbi, wq, wk, wvp, bq, bk, bv,
                                      qbuf, kbuf, vtbuf);
    flash_attn18<<<512, 256, 0, stream>>>(qbuf, kbuf, vtbuf, abuf);
    gemm_out<<<512, 256, 0, stream>>>(abuf, wo, bo, x, outp);
}

// Round 8
// 293.445 us; speedup vs baseline: 1.1796x; 1.0219x over previous
//
#include <hip/hip_runtime.h>
#include <hip/hip_bf16.h>

typedef unsigned short ushort_t;
typedef unsigned int uint_t;
typedef __attribute__((ext_vector_type(8))) short bf16x8;
typedef __attribute__((ext_vector_type(4))) float f32x4;

#define MFMA32(a, b, c) __builtin_amdgcn_mfma_f32_16x16x32_bf16(a, b, c, 0, 0, 0)

static constexpr int BATCH = 16;
static constexpr int SEQ   = 4096;   // H*W
static constexpr int CH    = 128;
static constexpr int NGRP  = 32;
static constexpr float EPS = 1e-6f;
// softmax scale folded into exp2 domain AND pre-folded into Q projection:
static constexpr float C2 = 0.08838834764831845f * 1.4426950408889634f;

__device__ inline ushort_t f2bf(float f) {
    uint_t u = __float_as_uint(f);
    u = (u + 0x7fff + ((u >> 16) & 1)) >> 16;
    return (ushort_t)u;
}

// bare v_exp_f32 via the clang intrinsic (schedulable, promotable — no inline
// asm).  Args bounded |x|<~35 in this kernel -> in-range, matches exp2f.
// (r16/r17/r18 A-B: inline-asm variants and s_setprio both induce ~17MB of
// scheduling spill traffic; this intrinsic alone is clean: 168.8->139.6us.)
__device__ inline float exp2_fast(float x) {
    return __builtin_amdgcn_exp2f(x);
}

// ---------------- weight prep: W fp32 [k][n] -> Wt bf16 [n][k] ----------------
// 4 blocks (Wq,Wk,Wv,Wo).  Coalesced fp32 reads, LDS transpose, 16B stores.
// 256KB output lives in L2 for the whole pipeline — every GEMM wave then
// loads B-fragments directly from global (L2 broadcast), eliminating all
// per-block W conversion (25M f2bf + scalar LDS stores) and inner barriers.
__global__ __launch_bounds__(256) void wprep(const float* __restrict__ W0,
                                             const float* __restrict__ W1,
                                             const float* __restrict__ W2,
                                             const float* __restrict__ W3,
                                             ushort_t* __restrict__ wt) {
    const float* Ws[4] = {W0, W1, W2, W3};
    const float* W = Ws[blockIdx.x];
    ushort_t* out = wt + (size_t)blockIdx.x * CH * CH;
    __shared__ ushort_t tile[128][130];
    int t = threadIdx.x;
    for (int i = 0; i < 16; ++i) {
        int idx = (t + i * 256) * 4;      // 16384 elems, 4 per thread-iter
        int kk = idx >> 7, n = idx & 127;
        float4 w4 = *(const float4*)(W + (size_t)kk * CH + n);
        tile[n + 0][kk] = f2bf(w4.x);
        tile[n + 1][kk] = f2bf(w4.y);
        tile[n + 2][kk] = f2bf(w4.z);
        tile[n + 3][kk] = f2bf(w4.w);
    }
    __syncthreads();
    for (int i = 0; i < 8; ++i) {
        int idx = (t + i * 256) * 8;
        int n = idx >> 7, kk = idx & 127;
        ushort_t tmp[8];
        for (int u = 0; u < 8; ++u) tmp[u] = tile[n][kk + u];
        *(uint4*)&out[(size_t)n * CH + kk] = *(const uint4*)tmp;
    }
}

// ---------------- GroupNorm partial sums (fp32 input) ----------------
// grid 256 = batch(16) x chunk(16); block 256. Writes RAW (sum, sumsq).
__global__ void gn_partial(const float* __restrict__ x, float* __restrict__ stats) {
    int bid = blockIdx.x;
    int b = bid >> 4, chunk = bid & 15;
    int t = threadIdx.x;
    int c4 = (t & 31) * 4;   // one group = 4 channels
    int rowoff = t >> 5;     // 0..7
    const float* xb = x + (size_t)b * SEQ * CH;
    float s1 = 0.f, s2 = 0.f;
    int base_row = chunk * 256;
    for (int i = 0; i < 32; ++i) {
        int r = base_row + i * 8 + rowoff;
        float4 v = *(const float4*)(xb + (size_t)r * CH + c4);
        s1 += v.x + v.y + v.z + v.w;
        s2 += v.x * v.x + v.y * v.y + v.z * v.z + v.w * v.w;
    }
    __shared__ float red[256][2];
    red[t][0] = s1; red[t][1] = s2;
    __syncthreads();
    if (t < 32) {
        float a1 = 0.f, a2 = 0.f;
        for (int ro = 0; ro < 8; ++ro) {
            a1 += red[ro * 32 + t][0];
            a2 += red[ro * 32 + t][1];
        }
        atomicAdd(&stats[(b * NGRP + t) * 2 + 0], a1);
        atomicAdd(&stats[(b * NGRP + t) * 2 + 1], a2);
    }
}

// ---------------- fused normalize + QKV GEMM (W^T bf16 from global) ----------
// r19: B-fragments load directly from precomputed Wt (L2-resident).  Only 2
// barriers per block (gstat, A-tile); no lds_w, no per-block f2bf of W.
// q pre-scaled by C2; v written TRANSPOSED vt[b][d][seq] with packed uint2
// stores (4 consecutive seq positions per store).
__global__ __launch_bounds__(256) void gemm_qkv(const float* __restrict__ x,
                                                const float* __restrict__ stats,
                                                const float* __restrict__ gsc,
                                                const float* __restrict__ gbi,
                                                const ushort_t* __restrict__ wt,
                                                const float* __restrict__ Bq,
                                                const float* __restrict__ Bk,
                                                const float* __restrict__ Bv,
                                                ushort_t* __restrict__ outq,
                                                ushort_t* __restrict__ outk,
                                                ushort_t* __restrict__ outvt) {
    __shared__ ushort_t lds_a[128][136];  // full 128x128 normalized A tile (bf16)
    __shared__ float2 gstat[32];
    int t = threadIdx.x;
    int wv = t >> 6, lane = t & 63, quad = lane >> 4, l16 = lane & 15;
    size_t m0 = (size_t)blockIdx.x * 128;
    int batch = (int)(m0 >> 12);
    int seq0  = (int)(m0 & 4095);
    // inline gn_finalize for this batch
    if (t < 32) {
        float sum = stats[(batch * NGRP + t) * 2 + 0];
        float sq  = stats[(batch * NGRP + t) * 2 + 1];
        float mean = sum / 16384.f;
        float var  = sq / 16384.f - mean * mean;
        gstat[t] = float2{mean, __frsqrt_rn(var + EPS)};
    }
    __syncthreads();
    // stage A once, normalizing x -> h in flight
    for (int i = 0; i < 8; ++i) {
        int idx = (t + i * 256) * 8;
        int r = idx >> 7, c = idx & 127;
        size_t row = m0 + r;
        float4 xa = *(const float4*)(x + row * CH + c);
        float4 xc = *(const float4*)(x + row * CH + c + 4);
        float2 stA = gstat[c >> 2];
        float2 stB = gstat[(c >> 2) + 1];
        float4 sA = *(const float4*)(gsc + c), sB = *(const float4*)(gsc + c + 4);
        float4 bA = *(const float4*)(gbi + c), bB = *(const float4*)(gbi + c + 4);
        ushort_t tmp[8];
        tmp[0] = f2bf((xa.x - stA.x) * stA.y * sA.x + bA.x);
        tmp[1] = f2bf((xa.y - stA.x) * stA.y * sA.y + bA.y);
        tmp[2] = f2bf((xa.z - stA.x) * stA.y * sA.z + bA.z);
        tmp[3] = f2bf((xa.w - stA.x) * stA.y * sA.w + bA.w);
        tmp[4] = f2bf((xc.x - stB.x) * stB.y * sB.x + bB.x);
        tmp[5] = f2bf((xc.y - stB.x) * stB.y * sB.y + bB.y);
        tmp[6] = f2bf((xc.z - stB.x) * stB.y * sB.z + bB.z);
        tmp[7] = f2bf((xc.w - stB.x) * stB.y * sB.w + bB.w);
        *(uint4*)&lds_a[r][c] = *(const uint4*)tmp;
    }
    __syncthreads();   // A tile ready; no further barriers needed
    for (int j = 0; j < 3; ++j) {
        const ushort_t* wtj = wt + (size_t)j * CH * CH;   // Wt[n][k] bf16
        const float* Bi = (j == 0) ? Bq : (j == 1) ? Bk : Bv;
        f32x4 acc[2][8] = {};
        for (int kh = 0; kh < 2; ++kh) {
            int k0 = kh * 64;
            for (int ks = 0; ks < 2; ++ks) {
                bf16x8 afrag[2];
                for (int tr = 0; tr < 2; ++tr)
                    afrag[tr] = *(const bf16x8*)&lds_a[wv * 32 + tr * 16 + l16][k0 + ks * 32 + quad * 8];
                for (int tc = 0; tc < 8; ++tc) {
                    bf16x8 bfrag = *(const bf16x8*)(wtj + (size_t)(tc * 16 + l16) * CH + k0 + ks * 32 + quad * 8);
                    for (int tr = 0; tr < 2; ++tr)
                        acc[tr][tc] = MFMA32(afrag[tr], bfrag, acc[tr][tc]);
                }
            }
        }
        // epilogue
        for (int tc = 0; tc < 8; ++tc) {
            int col = tc * 16 + l16;
            float bval = Bi[col];
            for (int tr = 0; tr < 2; ++tr) {
                int rl = wv * 32 + tr * 16 + quad * 4;
                if (j == 2) {
                    // V^T: rows rl..rl+3 are consecutive seq positions of col
                    ushort_t tmp[4];
                    for (int r = 0; r < 4; ++r) tmp[r] = f2bf(acc[tr][tc][r] + bval);
                    *(uint2*)&outvt[(size_t)batch * CH * SEQ + (size_t)col * SEQ + seq0 + rl] =
                        *(const uint2*)tmp;
                } else {
                    ushort_t* op = (j == 0) ? outq : outk;
                    for (int r = 0; r < 4; ++r) {
                        float vv = acc[tr][tc][r] + bval;
                        if (j == 0) vv *= C2;   // fold softmax scale into q
                        op[(m0 + rl + r) * CH + col] = f2bf(vv);
                    }
                }
            }
        }
    }
}

// ---------------- flash attention r18 (UNCHANGED — 139.6us verified) ---------
// Cross-iteration pipeline (QK_{i+1} fused with PV_i), unnormalized exp2
// softmax via __builtin_amdgcn_exp2f, dbuf, 1 barrier/iter, NO setprio.
__global__ __launch_bounds__(256, 2) void flash_attn18(const ushort_t* __restrict__ q,
                                                       const ushort_t* __restrict__ k,
                                                       const ushort_t* __restrict__ vt,
                                                       ushort_t* __restrict__ o) {
    int bid = blockIdx.x;
    int b = bid & 15, qt = bid >> 4;
    int t = threadIdx.x;
    int wv = t >> 6, lane = t & 63, quad = lane >> 4, l16 = lane & 15;
    const size_t SB = (size_t)SEQ * CH;
    const ushort_t* qb  = q  + (size_t)b * SB;
    const ushort_t* kb  = k  + (size_t)b * SB;
    const ushort_t* vtb = vt + (size_t)b * SB;   // [d][seq]

    __shared__ ushort_t lds_k[2][64][136];    // [buf][key][d]
    __shared__ ushort_t lds_vt[2][128][72];   // [buf][d][key_local PERMUTED]

    int qrow_base = qt * 128 + wv * 32;       // 4 waves x 32 q-rows
    bf16x8 qfrag[2][4];
#pragma unroll
    for (int nt = 0; nt < 2; ++nt)
#pragma unroll
        for (int ks = 0; ks < 4; ++ks)
            qfrag[nt][ks] = *(const bf16x8*)(qb + (size_t)(qrow_base + nt * 16 + l16) * CH + ks * 32 + quad * 8);

    f32x4 oacc[8][2] = {};        // [mt=d/16][nt]
    float psum[2] = {0.f, 0.f};   // per-lane partial row-sums (reduced at end)

    int kr_row  = t >> 4;          // 0..15 (+16i)
    int kr_col  = (t & 15) * 8;
    int vr_d    = t >> 3;          // 0..31 (+32i)
    int vr_beta = t & 7;
    int vc0 = 32 * (vr_beta >> 2) + 16 * (vr_beta & 1) + 4 * ((vr_beta >> 1) & 1);

    const ushort_t* kp = kb + (size_t)kr_row * CH + kr_col;
    const ushort_t* vp = vtb + (size_t)vr_d * SEQ + vr_beta * 8;

    uint4 kr[4], vr[4], k1[4];
#pragma unroll
    for (int i = 0; i < 4; ++i) kr[i] = *(const uint4*)(kp + (size_t)i * 16 * CH);
#pragma unroll
    for (int i = 0; i < 4; ++i) vr[i] = *(const uint4*)(vp + (size_t)i * 32 * SEQ);
#pragma unroll
    for (int i = 0; i < 4; ++i) k1[i] = *(const uint4*)(kp + (size_t)(64 + i * 16) * CH);
    kp += 2 * 64 * CH;   // -> tile 2
    vp += 64;            // -> tile 1
#pragma unroll
    for (int i = 0; i < 4; ++i) {
        *(uint4*)&lds_k[0][kr_row + 16 * i][kr_col] = kr[i];
        *(uint4*)&lds_k[1][kr_row + 16 * i][kr_col] = k1[i];
        *(uint2*)&lds_vt[0][vr_d + 32 * i][vc0]     = uint2{vr[i].x, vr[i].y};
        *(uint2*)&lds_vt[0][vr_d + 32 * i][vc0 + 8] = uint2{vr[i].z, vr[i].w};
    }
    __syncthreads();

    // prologue compute: QK_0 -> pkp_0 (unnormalized exp2)
    bf16x8 pkp[2][2];   // [nt][half], live across iterations
    {
        f32x4 s[4][2] = {};
#pragma unroll
        for (int ks = 0; ks < 4; ++ks) {
            bf16x8 kf[4];
#pragma unroll
            for (int kt = 0; kt < 4; ++kt)
                kf[kt] = *(const bf16x8*)&lds_k[0][kt * 16 + l16][ks * 32 + quad * 8];
#pragma unroll
            for (int kt = 0; kt < 4; ++kt) {
                s[kt][0] = MFMA32(kf[kt], qfrag[0][ks], s[kt][0]);
                s[kt][1] = MFMA32(kf[kt], qfrag[1][ks], s[kt][1]);
            }
        }
#pragma unroll
        for (int nt = 0; nt < 2; ++nt) {
            float ps = 0.f;
            uint_t pb[8];
#pragma unroll
            for (int kt = 0; kt < 4; ++kt) {
                float p0 = exp2_fast(s[kt][nt][0]);
                float p1 = exp2_fast(s[kt][nt][1]);
                float p2 = exp2_fast(s[kt][nt][2]);
                float p3 = exp2_fast(s[kt][nt][3]);
                ps += (p0 + p1) + (p2 + p3);
                __hip_bfloat162 h01 = __float22bfloat162_rn(float2{p0, p1});
                __hip_bfloat162 h23 = __float22bfloat162_rn(float2{p2, p3});
                __builtin_memcpy(&pb[kt * 2 + 0], &h01, 4);
                __builtin_memcpy(&pb[kt * 2 + 1], &h23, 4);
            }
            psum[nt] += ps;
            __builtin_memcpy(&pkp[nt][0], &pb[0], 16);
            __builtin_memcpy(&pkp[nt][1], &pb[4], 16);
        }
    }
    __syncthreads();   // all waves done reading lds_k[0] before iter0 overwrites it

    // main loop: iter it computes PV(tile it) + QK(tile it+1)
    for (int it = 0; it < 63; ++it) {
        int knxt = (it + 1) & 1;   // K_{it+1} read buffer; also V_{it+1} write buffer
        int vcur = it & 1;         // V_it read buffer;    also K_{it+2} write buffer
#pragma unroll
        for (int i = 0; i < 4; ++i) kr[i] = *(const uint4*)(kp + (size_t)i * 16 * CH);
#pragma unroll
        for (int i = 0; i < 4; ++i) vr[i] = *(const uint4*)(vp + (size_t)i * 32 * SEQ);
        kp += 64 * CH; vp += 64;

        // fused MFMA block: QK_{it+1} interleaved with PV_it
        f32x4 s[4][2] = {};
#pragma unroll
        for (int u = 0; u < 4; ++u) {
            bf16x8 kf[4];
#pragma unroll
            for (int kt = 0; kt < 4; ++kt)
                kf[kt] = *(const bf16x8*)&lds_k[knxt][kt * 16 + l16][u * 32 + quad * 8];
#pragma unroll
            for (int kt = 0; kt < 4; ++kt) {
                s[kt][0] = MFMA32(kf[kt], qfrag[0][u], s[kt][0]);
                s[kt][1] = MFMA32(kf[kt], qfrag[1][u], s[kt][1]);
            }
#pragma unroll
            for (int m2 = 0; m2 < 2; ++m2) {
                int mt = u * 2 + m2;
                bf16x8 vf0 = *(const bf16x8*)&lds_vt[vcur][mt * 16 + l16][quad * 8];
                bf16x8 vf1 = *(const bf16x8*)&lds_vt[vcur][mt * 16 + l16][32 + quad * 8];
                oacc[mt][0] = MFMA32(vf0, pkp[0][0], oacc[mt][0]);
                oacc[mt][0] = MFMA32(vf1, pkp[0][1], oacc[mt][0]);
                oacc[mt][1] = MFMA32(vf0, pkp[1][0], oacc[mt][1]);
                oacc[mt][1] = MFMA32(vf1, pkp[1][1], oacc[mt][1]);
            }
        }

        // softmax(tile it+1) -> pkp for next iteration (overlaps store tail)
#pragma unroll
        for (int nt = 0; nt < 2; ++nt) {
            float ps = 0.f;
            uint_t pb[8];
#pragma unroll
            for (int kt = 0; kt < 4; ++kt) {
                float p0 = exp2_fast(s[kt][nt][0]);
                float p1 = exp2_fast(s[kt][nt][1]);
                float p2 = exp2_fast(s[kt][nt][2]);
                float p3 = exp2_fast(s[kt][nt][3]);
                ps += (p0 + p1) + (p2 + p3);
                __hip_bfloat162 h01 = __float22bfloat162_rn(float2{p0, p1});
                __hip_bfloat162 h23 = __float22bfloat162_rn(float2{p2, p3});
                __builtin_memcpy(&pb[kt * 2 + 0], &h01, 4);
                __builtin_memcpy(&pb[kt * 2 + 1], &h23, 4);
            }
            psum[nt] += ps;
            __builtin_memcpy(&pkp[nt][0], &pb[0], 16);
            __builtin_memcpy(&pkp[nt][1], &pb[4], 16);
        }

        // stage writes: K_{it+2} -> lds_k[vcur], V_{it+1} -> lds_vt[knxt]
#pragma unroll
        for (int i = 0; i < 4; ++i) {
            *(uint4*)&lds_k[vcur][kr_row + 16 * i][kr_col] = kr[i];
            *(uint2*)&lds_vt[knxt][vr_d + 32 * i][vc0]     = uint2{vr[i].x, vr[i].y};
            *(uint2*)&lds_vt[knxt][vr_d + 32 * i][vc0 + 8] = uint2{vr[i].z, vr[i].w};
        }
        __syncthreads();   // single barrier per iteration
    }

    // epilogue: PV for tile 63 (lds_vt[1], pkp_63 computed at it=62)
#pragma unroll
    for (int mt = 0; mt < 8; ++mt) {
        bf16x8 vf0 = *(const bf16x8*)&lds_vt[1][mt * 16 + l16][quad * 8];
        bf16x8 vf1 = *(const bf16x8*)&lds_vt[1][mt * 16 + l16][32 + quad * 8];
        oacc[mt][0] = MFMA32(vf0, pkp[0][0], oacc[mt][0]);
        oacc[mt][0] = MFMA32(vf1, pkp[0][1], oacc[mt][0]);
        oacc[mt][1] = MFMA32(vf0, pkp[1][0], oacc[mt][1]);
        oacc[mt][1] = MFMA32(vf1, pkp[1][1], oacc[mt][1]);
    }

    // epilogue: cross-lane row-sum reduce (ONCE), then O[qrow][d] = O^T / l
#pragma unroll
    for (int nt = 0; nt < 2; ++nt) {
        float tot = psum[nt];
        tot += __shfl_xor(tot, 16, 64);
        tot += __shfl_xor(tot, 32, 64);
        float inv = 1.f / tot;
        size_t row = (size_t)b * SEQ + qrow_base + nt * 16 + l16;
#pragma unroll
        for (int mt = 0; mt < 8; ++mt) {
            ushort_t tmp[4];
#pragma unroll
            for (int r = 0; r < 4; ++r) tmp[r] = f2bf(oacc[mt][nt][r] * inv);
            *(uint2*)&o[row * CH + mt * 16 + quad * 4] = *(const uint2*)tmp;
        }
    }
}

// ---------------- final GEMM: out = A_bf16 @ Wo + bias + resid (fp32 out) ----
// r19: B-fragments direct from global Wt (L2-resident); only 1 barrier.
__global__ __launch_bounds__(256) void gemm_out(const ushort_t* __restrict__ A,
                                                const ushort_t* __restrict__ wto,
                                                const float* __restrict__ bias,
                                                const float* __restrict__ resid,
                                                float* __restrict__ out) {
    __shared__ ushort_t lds_a[128][136];
    int t = threadIdx.x;
    int wv = t >> 6, lane = t & 63, quad = lane >> 4, l16 = lane & 15;
    size_t m0 = (size_t)blockIdx.x * 128;
    // stage full A tile (bf16, vector copy)
    for (int i = 0; i < 8; ++i) {
        int idx = (t + i * 256) * 8;
        int r = idx >> 7, c = idx & 127;
        *(uint4*)&lds_a[r][c] = *(const uint4*)(A + (m0 + r) * CH + c);
    }
    __syncthreads();
    f32x4 acc[2][8] = {};
    for (int kh = 0; kh < 2; ++kh) {
        int k0 = kh * 64;
        for (int ks = 0; ks < 2; ++ks) {
            bf16x8 afrag[2];
            for (int tr = 0; tr < 2; ++tr)
                afrag[tr] = *(const bf16x8*)&lds_a[wv * 32 + tr * 16 + l16][k0 + ks * 32 + quad * 8];
            for (int tc = 0; tc < 8; ++tc) {
                bf16x8 bfrag = *(const bf16x8*)(wto + (size_t)(tc * 16 + l16) * CH + k0 + ks * 32 + quad * 8);
                for (int tr = 0; tr < 2; ++tr)
                    acc[tr][tc] = MFMA32(afrag[tr], bfrag, acc[tr][tc]);
            }
        }
    }
    for (int tc = 0; tc < 8; ++tc) {
        int col = tc * 16 + l16;
        float bval = bias[col];
        for (int tr = 0; tr < 2; ++tr) {
            int rl = wv * 32 + tr * 16 + quad * 4;
            for (int r = 0; r < 4; ++r) {
                size_t row = m0 + rl + r;
                out[row * CH + col] = acc[tr][tc][r] + bval + resid[row * CH + col];
            }
        }
    }
}

extern "C" void kernel_launch(void* const* d_in, const int* in_sizes, int n_in,
                              void* d_out, int out_size, void* d_ws, size_t ws_size,
                              hipStream_t stream) {
    const float* x   = (const float*)d_in[0];
    const float* gsc = (const float*)d_in[1];
    const float* gbi = (const float*)d_in[2];
    const float* wq  = (const float*)d_in[3];
    const float* bq  = (const float*)d_in[4];
    const float* wk  = (const float*)d_in[5];
    const float* bk  = (const float*)d_in[6];
    const float* wvp = (const float*)d_in[7];
    const float* bv  = (const float*)d_in[8];
    const float* wo  = (const float*)d_in[9];
    const float* bo  = (const float*)d_in[10];
    float* outp = (float*)d_out;

    const size_t NELEM = (size_t)BATCH * SEQ * CH;  // 8388608
    float*    stats = (float*)d_ws;
    ushort_t* qbuf  = (ushort_t*)((char*)d_ws + 4096);
    ushort_t* kbuf  = qbuf + NELEM;
    ushort_t* vtbuf = kbuf + NELEM;
    ushort_t* abuf  = vtbuf + NELEM;   // attention output
    ushort_t* wtbuf = abuf + NELEM;    // 4 x 128x128 bf16 W^T (256 KB)
    // note: flash_attn18 prefetches one K tile past the K buffer end (reads
    // land in vtbuf; values unused) — keep buffer order qbuf,kbuf,vtbuf,abuf.

    hipMemsetAsync(stats, 0, BATCH * NGRP * 2 * sizeof(float), stream);
    wprep<<<4, 256, 0, stream>>>(wq, wk, wvp, wo, wtbuf);
    gn_partial<<<256, 256, 0, stream>>>(x, stats);
    gemm_qkv<<<512, 256, 0, stream>>>(x, stats, gsc, gbi, wtbuf, bq, bk, bv,
                                      qbuf, kbuf, vtbuf);
    flash_attn18<<<512, 512 / 2, 0, stream>>>(qbuf, kbuf, vtbuf, abuf);
    gemm_out<<<512, 256, 0, stream>>>(abuf, wtbuf + 3 * CH * CH, bo, x, outp);
}